// Round 4
// baseline (1696.883 us; speedup 1.0000x reference)
//
#include <hip/hip_runtime.h>

#define N_NODES 100000
#define N_EDGES 1600000
#define HID 256
#define NSEG (N_NODES * 4)   // 4 src-buckets per node

typedef _Float16 half_t;
using f16x8 = __attribute__((ext_vector_type(8))) half_t;
using f32x4 = __attribute__((ext_vector_type(4))) float;

constexpr int SCAN_CHUNK = 1024;
constexpr int NBLK2 = (NSEG + SCAN_CHUNK - 1) / SCAN_CHUNK; // 391

#define GLOAD_LDS16(gp, lp)                                                    \
    __builtin_amdgcn_global_load_lds(                                         \
        (const __attribute__((address_space(1))) void*)(gp),                  \
        (__attribute__((address_space(3))) void*)(lp), 16, 0, 0)

// ---------------- CSR build (segmented by dst*4 + src-bucket) ----------------
__global__ void k_count_deg(const int* __restrict__ dst, int* __restrict__ degT) {
    int e = blockIdx.x * 256 + threadIdx.x;
    if (e < N_EDGES) atomicAdd(&degT[dst[e]], 1);
}

__global__ void k_count_seg(const int* __restrict__ src, const int* __restrict__ dst,
                            int* __restrict__ deg2) {
    int e = blockIdx.x * 256 + threadIdx.x;
    if (e < N_EDGES) {
        int b = src[e] >> 15;  // 4 buckets of 32768 src-rows (33.5 MB slice)
        atomicAdd(&deg2[dst[e] * 4 + b], 1);
    }
}

__global__ void k_blocksum(const int* __restrict__ deg, int* __restrict__ bsum, int n) {
    __shared__ int sm[4];
    int b = blockIdx.x, t = threadIdx.x;
    int base = b * SCAN_CHUNK;
    int s = 0;
    for (int i = 0; i < 4; ++i) {
        int idx = base + t + i * 256;
        if (idx < n) s += deg[idx];
    }
    for (int off = 32; off; off >>= 1) s += __shfl_down(s, off);
    if ((t & 63) == 0) sm[t >> 6] = s;
    __syncthreads();
    if (t == 0) bsum[b] = sm[0] + sm[1] + sm[2] + sm[3];
}

__global__ void k_scan_bsum(const int* __restrict__ bsum, int* __restrict__ bscan, int nblk) {
    if (threadIdx.x == 0) {
        int r = 0;
        for (int i = 0; i < nblk; ++i) { bscan[i] = r; r += bsum[i]; }
    }
}

__global__ void k_scan_final(const int* __restrict__ deg, const int* __restrict__ bscan,
                             int* __restrict__ offsets, int* __restrict__ cursor, int n) {
    __shared__ int sm[256];
    int b = blockIdx.x, t = threadIdx.x;
    int base = b * SCAN_CHUNK + t * 4;
    int c[4];
    for (int e = 0; e < 4; ++e) {
        int idx = base + e;
        c[e] = (idx < n) ? deg[idx] : 0;
    }
    int s = c[0] + c[1] + c[2] + c[3];
    sm[t] = s;
    __syncthreads();
    for (int off = 1; off < 256; off <<= 1) {
        int v = (t >= off) ? sm[t - off] : 0;
        __syncthreads();
        sm[t] += v;
        __syncthreads();
    }
    int run = sm[t] - s + bscan[b];
    for (int e = 0; e < 4; ++e) {
        int idx = base + e;
        if (idx < n) { offsets[idx] = run; cursor[idx] = run; }
        run += c[e];
    }
}

__global__ void k_fill_seg(const int* __restrict__ src, const int* __restrict__ dst,
                           int* __restrict__ cursor, int* __restrict__ csr) {
    int e = blockIdx.x * 256 + threadIdx.x;
    if (e < N_EDGES) {
        int s = src[e];
        int b = s >> 15;
        int pos = atomicAdd(&cursor[dst[e] * 4 + b], 1);
        csr[pos] = s;
    }
}

// ---------------- bucketed mean aggregation ----------------
// mode 0: init (agg = sum_b0), 1: mid (agg += sum_b), 2: final (agg = (agg+sum)/deg)
__global__ __launch_bounds__(256) void k_aggregate_b(
    const float* __restrict__ x, const int* __restrict__ offsets2,
    const int* __restrict__ deg2, const int* __restrict__ degT,
    const int* __restrict__ csr, float* __restrict__ agg,
    int bucket, int mode) {
    int wave = threadIdx.x >> 6;
    int lane = threadIdx.x & 63;
    int node = blockIdx.x * 4 + wave;
    int seg = node * 4 + bucket;
    int off = offsets2[seg];
    int len = deg2[seg];
    if (mode == 1 && len == 0) return;
    const size_t lo = (size_t)lane * 4;
    float4 a0 = {0.f, 0.f, 0.f, 0.f}, a1 = a0, a2 = a0, a3 = a0;
    int j = 0;
    for (; j + 4 <= len; j += 4) {
        int s0 = csr[off + j + 0];
        int s1 = csr[off + j + 1];
        int s2 = csr[off + j + 2];
        int s3 = csr[off + j + 3];
        float4 v0 = *reinterpret_cast<const float4*>(x + (size_t)s0 * HID + lo);
        float4 v1 = *reinterpret_cast<const float4*>(x + (size_t)s1 * HID + lo);
        float4 v2 = *reinterpret_cast<const float4*>(x + (size_t)s2 * HID + lo);
        float4 v3 = *reinterpret_cast<const float4*>(x + (size_t)s3 * HID + lo);
        a0.x += v0.x; a0.y += v0.y; a0.z += v0.z; a0.w += v0.w;
        a1.x += v1.x; a1.y += v1.y; a1.z += v1.z; a1.w += v1.w;
        a2.x += v2.x; a2.y += v2.y; a2.z += v2.z; a2.w += v2.w;
        a3.x += v3.x; a3.y += v3.y; a3.z += v3.z; a3.w += v3.w;
    }
    for (; j < len; ++j) {
        int s = csr[off + j];
        float4 v = *reinterpret_cast<const float4*>(x + (size_t)s * HID + lo);
        a0.x += v.x; a0.y += v.y; a0.z += v.z; a0.w += v.w;
    }
    float4 acc;
    acc.x = (a0.x + a1.x) + (a2.x + a3.x);
    acc.y = (a0.y + a1.y) + (a2.y + a3.y);
    acc.z = (a0.z + a1.z) + (a2.z + a3.z);
    acc.w = (a0.w + a1.w) + (a2.w + a3.w);
    float* ap = agg + (size_t)node * HID + lo;
    if (mode != 0) {
        float4 prev = *reinterpret_cast<const float4*>(ap);
        acc.x += prev.x; acc.y += prev.y; acc.z += prev.z; acc.w += prev.w;
    }
    if (mode == 2) {
        int dg = degT[node];
        float inv = 1.0f / (float)(dg > 0 ? dg : 1);
        acc.x *= inv; acc.y *= inv; acc.z *= inv; acc.w *= inv;
    }
    *reinterpret_cast<float4*>(ap) = acc;
}

// ---------------- plain single-pass aggregation (A/B control, layer 2) -----
__global__ __launch_bounds__(256) void k_aggregate_plain(
    const float* __restrict__ x, const int* __restrict__ offsets2,
    const int* __restrict__ degT, const int* __restrict__ csr,
    float* __restrict__ agg) {
    int wave = threadIdx.x >> 6;
    int lane = threadIdx.x & 63;
    int node = blockIdx.x * 4 + wave;
    int off = offsets2[node * 4];  // buckets contiguous per node
    int dg = degT[node];
    const size_t lo = (size_t)lane * 4;
    float4 a0 = {0.f, 0.f, 0.f, 0.f}, a1 = a0, a2 = a0, a3 = a0;
    int j = 0;
    for (; j + 4 <= dg; j += 4) {
        int s0 = csr[off + j + 0];
        int s1 = csr[off + j + 1];
        int s2 = csr[off + j + 2];
        int s3 = csr[off + j + 3];
        float4 v0 = *reinterpret_cast<const float4*>(x + (size_t)s0 * HID + lo);
        float4 v1 = *reinterpret_cast<const float4*>(x + (size_t)s1 * HID + lo);
        float4 v2 = *reinterpret_cast<const float4*>(x + (size_t)s2 * HID + lo);
        float4 v3 = *reinterpret_cast<const float4*>(x + (size_t)s3 * HID + lo);
        a0.x += v0.x; a0.y += v0.y; a0.z += v0.z; a0.w += v0.w;
        a1.x += v1.x; a1.y += v1.y; a1.z += v1.z; a1.w += v1.w;
        a2.x += v2.x; a2.y += v2.y; a2.z += v2.z; a2.w += v2.w;
        a3.x += v3.x; a3.y += v3.y; a3.z += v3.z; a3.w += v3.w;
    }
    for (; j < dg; ++j) {
        int s = csr[off + j];
        float4 v = *reinterpret_cast<const float4*>(x + (size_t)s * HID + lo);
        a0.x += v.x; a0.y += v.y; a0.z += v.z; a0.w += v.w;
    }
    float4 acc;
    acc.x = (a0.x + a1.x) + (a2.x + a3.x);
    acc.y = (a0.y + a1.y) + (a2.y + a3.y);
    acc.z = (a0.z + a1.z) + (a2.z + a3.z);
    acc.w = (a0.w + a1.w) + (a2.w + a3.w);
    float inv = 1.0f / (float)(dg > 0 ? dg : 1);
    acc.x *= inv; acc.y *= inv; acc.z *= inv; acc.w *= inv;
    *reinterpret_cast<float4*>(agg + (size_t)node * HID + lo) = acc;
}

// ---------------- weight split+transpose ----------------
__global__ void k_splitw(const float* __restrict__ W, half_t* __restrict__ out, int ncols) {
    int col = blockIdx.x;
    int k = threadIdx.x;
    float v = W[(size_t)k * ncols + col];
    half_t h = (half_t)v;
    out[(size_t)col * 256 + k] = h;
    out[(size_t)ncols * 256 + (size_t)col * 256 + k] = (half_t)(v - (float)h);
}

// ---------------- fp16x3 MFMA GEMM ----------------
template <int BN>
__global__ __launch_bounds__(512, 4) void k_gemm_mfma(
    const float* __restrict__ A1, const half_t* __restrict__ B1,
    const float* __restrict__ A2, const half_t* __restrict__ B2,
    const float* __restrict__ bias, float* __restrict__ C,
    int M, int doRelu) {
    constexpr int WNW = BN / 4;
    constexpr int NF = WNW / 16;
    __shared__ f16x8 sAhi[512];
    __shared__ f16x8 sAlo[512];
    __shared__ f16x8 sB[8 * BN];

    const int tid = threadIdx.x;
    const int lane = tid & 63;
    const int m0 = blockIdx.x * 128;
    const int skg = tid >> 7;
    const int srow = tid & 127;
    const int grow = min(m0 + srow, M - 1);
    const int l16 = lane & 15, fkg = lane >> 4;
    const int wid = tid >> 6, wm = wid >> 2, wn = wid & 3;
    const int aBase = fkg * 128 + wm * 64 + l16;
    const int bBase = fkg * BN + wn * WNW + l16;

    f32x4 acc[4][NF] = {};

    for (int op = 0; op < 2; ++op) {
        const float* A = op ? A2 : A1;
        const half_t* B = op ? B2 : B1;
        if (!A) break;
        const float* aptr = A + (size_t)grow * 256 + skg * 8;
        float4 f0 = *reinterpret_cast<const float4*>(aptr);
        float4 f1 = *reinterpret_cast<const float4*>(aptr + 4);

        for (int s = 0; s < 8; ++s) {
            const int kk = s * 32;
            __syncthreads();
#pragma unroll
            for (int b = 0; b < BN / 128; ++b) {
                int c = tid + b * 512;
                int col = c & (BN - 1);
                int ckg = (BN == 256) ? (c >> 8) : (c >> 7);
                const half_t* bh = B + (size_t)col * 256 + kk + ckg * 8;
                GLOAD_LDS16(bh, &sB[c]);
                GLOAD_LDS16(bh + (size_t)BN * 256, &sB[4 * BN + c]);
            }
            {
                float fv[8] = {f0.x, f0.y, f0.z, f0.w, f1.x, f1.y, f1.z, f1.w};
                f16x8 hi, lo;
#pragma unroll
                for (int j = 0; j < 8; ++j) {
                    half_t h = (half_t)fv[j];
                    hi[j] = h;
                    lo[j] = (half_t)(fv[j] - (float)h);
                }
                sAhi[tid] = hi;
                sAlo[tid] = lo;
            }
            __syncthreads();
            if (s < 7) {
                f0 = *reinterpret_cast<const float4*>(aptr + (s + 1) * 32);
                f1 = *reinterpret_cast<const float4*>(aptr + (s + 1) * 32 + 4);
            }
            f16x8 ah[4], al[4];
#pragma unroll
            for (int mf = 0; mf < 4; ++mf) {
                ah[mf] = sAhi[aBase + mf * 16];
                al[mf] = sAlo[aBase + mf * 16];
            }
#pragma unroll
            for (int nf = 0; nf < NF; ++nf) {
                f16x8 bh = sB[bBase + nf * 16];
                f16x8 bl = sB[4 * BN + bBase + nf * 16];
#pragma unroll
                for (int mf = 0; mf < 4; ++mf) {
                    acc[mf][nf] = __builtin_amdgcn_mfma_f32_16x16x32_f16(ah[mf], bh, acc[mf][nf], 0, 0, 0);
                    acc[mf][nf] = __builtin_amdgcn_mfma_f32_16x16x32_f16(al[mf], bh, acc[mf][nf], 0, 0, 0);
                    acc[mf][nf] = __builtin_amdgcn_mfma_f32_16x16x32_f16(ah[mf], bl, acc[mf][nf], 0, 0, 0);
                }
            }
        }
    }

#pragma unroll
    for (int mf = 0; mf < 4; ++mf) {
        int row = m0 + wm * 64 + mf * 16 + (lane >> 4) * 4;
#pragma unroll
        for (int nf = 0; nf < NF; ++nf) {
            int col = wn * WNW + nf * 16 + l16;
            float bv = bias[col];
#pragma unroll
            for (int r = 0; r < 4; ++r) {
                int gr = row + r;
                if (gr < M) {
                    float v = acc[mf][nf][r] + bv;
                    if (doRelu) v = fmaxf(v, 0.f);
                    C[(size_t)gr * BN + col] = v;
                }
            }
        }
    }
}

// ---------------- head ----------------
__global__ void k_head(const float* __restrict__ h, const float* __restrict__ W2,
                       const float* __restrict__ b2, float* __restrict__ out) {
    int wave = threadIdx.x >> 6, lane = threadIdx.x & 63;
    int node = blockIdx.x * 4 + wave;
    const float* hr = h + (size_t)node * 128;
    float p0 = 0.f, p1 = 0.f, p2 = 0.f, p3 = 0.f;
    for (int j = lane; j < 128; j += 64) {
        float hv = hr[j];
        p0 += hv * W2[j * 4 + 0];
        p1 += hv * W2[j * 4 + 1];
        p2 += hv * W2[j * 4 + 2];
        p3 += hv * W2[j * 4 + 3];
    }
    for (int off = 32; off; off >>= 1) {
        p0 += __shfl_down(p0, off);
        p1 += __shfl_down(p1, off);
        p2 += __shfl_down(p2, off);
        p3 += __shfl_down(p3, off);
    }
    if (lane == 0) {
        float4 o = {p0 + b2[0], p1 + b2[1], p2 + b2[2], p3 + b2[3]};
        *reinterpret_cast<float4*>(out + (size_t)node * 4) = o;
    }
}

extern "C" void kernel_launch(void* const* d_in, const int* in_sizes, int n_in,
                              void* d_out, int out_size, void* d_ws, size_t ws_size,
                              hipStream_t stream) {
    const float* x  = (const float*)d_in[0];
    const int*   ei = (const int*)d_in[1];
    const float* Wl = (const float*)d_in[2];
    const float* bl = (const float*)d_in[3];
    const float* Wr = (const float*)d_in[4];
    const float* W1 = (const float*)d_in[5];
    const float* b1 = (const float*)d_in[6];
    const float* W2 = (const float*)d_in[7];
    const float* b2 = (const float*)d_in[8];
    float* out = (float*)d_out;

    char* w = (char*)d_ws;
    size_t o = 0;
    auto alloc = [&](size_t bytes) -> void* {
        void* p = w + o;
        o += (bytes + 255) & ~(size_t)255;
        return p;
    };
    int* degT     = (int*)alloc((size_t)N_NODES * 4);
    int* deg2     = (int*)alloc((size_t)NSEG * 4);
    int* cursor2  = (int*)alloc((size_t)NSEG * 4);
    int* offsets2 = (int*)alloc((size_t)NSEG * 4);
    int* bsum     = (int*)alloc((size_t)NBLK2 * 4);
    int* bscan    = (int*)alloc((size_t)NBLK2 * 4);
    int* csr      = (int*)alloc((size_t)N_EDGES * 4);
    float* agg    = (float*)alloc((size_t)N_NODES * HID * 4);
    float* feat   = (float*)alloc((size_t)N_NODES * HID * 4);
    half_t* WlT[3]; half_t* WrT[3];
    for (int l = 0; l < 3; ++l) {
        WlT[l] = (half_t*)alloc((size_t)256 * 256 * 2 * 2);
        WrT[l] = (half_t*)alloc((size_t)256 * 256 * 2 * 2);
    }
    half_t* W1T = (half_t*)alloc((size_t)128 * 256 * 2 * 2);
    float* h = agg;

    const int* srcA = ei;
    const int* dstA = ei + N_EDGES;

    for (int l = 0; l < 3; ++l) {
        k_splitw<<<256, 256, 0, stream>>>(Wl + (size_t)l * 65536, WlT[l], 256);
        k_splitw<<<256, 256, 0, stream>>>(Wr + (size_t)l * 65536, WrT[l], 256);
    }
    k_splitw<<<128, 256, 0, stream>>>(W1, W1T, 128);

    // CSR build (segmented)
    hipMemsetAsync(degT, 0, (size_t)N_NODES * 4, stream);
    hipMemsetAsync(deg2, 0, (size_t)NSEG * 4, stream);
    k_count_deg<<<(N_EDGES + 255) / 256, 256, 0, stream>>>(dstA, degT);
    k_count_seg<<<(N_EDGES + 255) / 256, 256, 0, stream>>>(srcA, dstA, deg2);
    k_blocksum<<<NBLK2, 256, 0, stream>>>(deg2, bsum, NSEG);
    k_scan_bsum<<<1, 64, 0, stream>>>(bsum, bscan, NBLK2);
    k_scan_final<<<NBLK2, 256, 0, stream>>>(deg2, bscan, offsets2, cursor2, NSEG);
    k_fill_seg<<<(N_EDGES + 255) / 256, 256, 0, stream>>>(srcA, dstA, cursor2, csr);

    const int mblocks = (N_NODES + 127) / 128;
    const int ablocks = N_NODES / 4;
    const float* xin = x;
    for (int l = 0; l < 3; ++l) {
        if (l < 2) {
            // bucketed: 4 passes, each reads a 33.5 MB src slice
            for (int b = 0; b < 4; ++b) {
                int mode = (b == 0) ? 0 : (b == 3 ? 2 : 1);
                k_aggregate_b<<<ablocks, 256, 0, stream>>>(
                    xin, offsets2, deg2, degT, csr, agg, b, mode);
            }
        } else {
            // plain single-pass (A/B control)
            k_aggregate_plain<<<ablocks, 256, 0, stream>>>(xin, offsets2, degT, csr, agg);
        }
        k_gemm_mfma<256><<<mblocks, 512, 0, stream>>>(
            agg, WlT[l], xin, WrT[l], bl + (size_t)l * 256, feat, N_NODES, 1);
        xin = feat;
    }
    k_gemm_mfma<128><<<mblocks, 512, 0, stream>>>(
        feat, W1T, nullptr, nullptr, b1, h, N_NODES, 1);
    k_head<<<N_NODES / 4, 256, 0, stream>>>(h, W2, b2, out);
}

// Round 5
// 1106.682 us; speedup vs baseline: 1.5333x; 1.5333x over previous
//
#include <hip/hip_runtime.h>

#define N_NODES 100000
#define N_EDGES 1600000
#define HID 256

typedef _Float16 half_t;
using f16x8 = __attribute__((ext_vector_type(8))) half_t;
using f16x4 = __attribute__((ext_vector_type(4))) half_t;
using f32x4 = __attribute__((ext_vector_type(4))) float;

constexpr int SCAN_CHUNK = 1024;
constexpr int NBLK = (N_NODES + SCAN_CHUNK - 1) / SCAN_CHUNK; // 98

#define GLOAD_LDS16(gp, lp)                                                    \
    __builtin_amdgcn_global_load_lds(                                         \
        (const __attribute__((address_space(1))) void*)(gp),                  \
        (__attribute__((address_space(3))) void*)(lp), 16, 0, 0)

// ---------------- CSR build ----------------
__global__ void k_count(const int* __restrict__ dst, int* __restrict__ deg) {
    int e = blockIdx.x * 256 + threadIdx.x;
    if (e < N_EDGES) atomicAdd(&deg[dst[e]], 1);
}

__global__ void k_blocksum(const int* __restrict__ deg, int* __restrict__ bsum) {
    __shared__ int sm[4];
    int b = blockIdx.x, t = threadIdx.x;
    int base = b * SCAN_CHUNK;
    int s = 0;
    for (int i = 0; i < 4; ++i) {
        int idx = base + t + i * 256;
        if (idx < N_NODES) s += deg[idx];
    }
    for (int off = 32; off; off >>= 1) s += __shfl_down(s, off);
    if ((t & 63) == 0) sm[t >> 6] = s;
    __syncthreads();
    if (t == 0) bsum[b] = sm[0] + sm[1] + sm[2] + sm[3];
}

__global__ void k_scan_bsum(const int* __restrict__ bsum, int* __restrict__ bscan) {
    if (threadIdx.x == 0) {
        int r = 0;
        for (int i = 0; i < NBLK; ++i) { bscan[i] = r; r += bsum[i]; }
    }
}

__global__ void k_scan_final(const int* __restrict__ deg, const int* __restrict__ bscan,
                             int* __restrict__ offsets, int* __restrict__ cursor) {
    __shared__ int sm[256];
    int b = blockIdx.x, t = threadIdx.x;
    int base = b * SCAN_CHUNK + t * 4;
    int c[4];
    for (int e = 0; e < 4; ++e) {
        int idx = base + e;
        c[e] = (idx < N_NODES) ? deg[idx] : 0;
    }
    int s = c[0] + c[1] + c[2] + c[3];
    sm[t] = s;
    __syncthreads();
    for (int off = 1; off < 256; off <<= 1) {
        int v = (t >= off) ? sm[t - off] : 0;
        __syncthreads();
        sm[t] += v;
        __syncthreads();
    }
    int run = sm[t] - s + bscan[b];
    for (int e = 0; e < 4; ++e) {
        int idx = base + e;
        if (idx < N_NODES) { offsets[idx] = run; cursor[idx] = run; }
        run += c[e];
    }
}

__global__ void k_fill(const int* __restrict__ src, const int* __restrict__ dst,
                       int* __restrict__ cursor, int* __restrict__ csr) {
    int e = blockIdx.x * 256 + threadIdx.x;
    if (e < N_EDGES) {
        int d = dst[e];
        int pos = atomicAdd(&cursor[d], 1);
        csr[pos] = src[e];
    }
}

// ---------------- fp32 -> fp16 convert (8 elems/thread) ----------------
__global__ void k_tohalf(const float* __restrict__ in, half_t* __restrict__ out, int n8) {
    int i = blockIdx.x * 256 + threadIdx.x;
    if (i < n8) {
        float4 a = *reinterpret_cast<const float4*>(in + (size_t)i * 8);
        float4 b = *reinterpret_cast<const float4*>(in + (size_t)i * 8 + 4);
        f16x8 h;
        h[0] = (half_t)a.x; h[1] = (half_t)a.y; h[2] = (half_t)a.z; h[3] = (half_t)a.w;
        h[4] = (half_t)b.x; h[5] = (half_t)b.y; h[6] = (half_t)b.z; h[7] = (half_t)b.w;
        *reinterpret_cast<f16x8*>(out + (size_t)i * 8) = h;
    }
}

// ---------------- mean aggregation, fp16 features (wave/node, 4x unroll) ---
__global__ __launch_bounds__(256) void k_aggregate_h(
    const half_t* __restrict__ xh, const int* __restrict__ offsets,
    const int* __restrict__ deg, const int* __restrict__ csr,
    float* __restrict__ agg) {
    int wave = threadIdx.x >> 6;
    int lane = threadIdx.x & 63;
    int node = blockIdx.x * 4 + wave;
    int off = offsets[node];
    int dg = deg[node];
    const size_t lo = (size_t)lane * 4;
    float4 a0 = {0.f, 0.f, 0.f, 0.f}, a1 = a0, a2 = a0, a3 = a0;
    int j = 0;
    for (; j + 4 <= dg; j += 4) {
        int s0 = csr[off + j + 0];
        int s1 = csr[off + j + 1];
        int s2 = csr[off + j + 2];
        int s3 = csr[off + j + 3];
        f16x4 v0 = *reinterpret_cast<const f16x4*>(xh + (size_t)s0 * HID + lo);
        f16x4 v1 = *reinterpret_cast<const f16x4*>(xh + (size_t)s1 * HID + lo);
        f16x4 v2 = *reinterpret_cast<const f16x4*>(xh + (size_t)s2 * HID + lo);
        f16x4 v3 = *reinterpret_cast<const f16x4*>(xh + (size_t)s3 * HID + lo);
        a0.x += (float)v0[0]; a0.y += (float)v0[1]; a0.z += (float)v0[2]; a0.w += (float)v0[3];
        a1.x += (float)v1[0]; a1.y += (float)v1[1]; a1.z += (float)v1[2]; a1.w += (float)v1[3];
        a2.x += (float)v2[0]; a2.y += (float)v2[1]; a2.z += (float)v2[2]; a2.w += (float)v2[3];
        a3.x += (float)v3[0]; a3.y += (float)v3[1]; a3.z += (float)v3[2]; a3.w += (float)v3[3];
    }
    for (; j < dg; ++j) {
        int s = csr[off + j];
        f16x4 v = *reinterpret_cast<const f16x4*>(xh + (size_t)s * HID + lo);
        a0.x += (float)v[0]; a0.y += (float)v[1]; a0.z += (float)v[2]; a0.w += (float)v[3];
    }
    float4 acc;
    acc.x = (a0.x + a1.x) + (a2.x + a3.x);
    acc.y = (a0.y + a1.y) + (a2.y + a3.y);
    acc.z = (a0.z + a1.z) + (a2.z + a3.z);
    acc.w = (a0.w + a1.w) + (a2.w + a3.w);
    float inv = 1.0f / (float)(dg > 0 ? dg : 1);
    acc.x *= inv; acc.y *= inv; acc.z *= inv; acc.w *= inv;
    *reinterpret_cast<float4*>(agg + (size_t)node * HID + lo) = acc;
}

// ---------------- weight split+transpose: hi[col][k] then lo[col][k] -------
__global__ void k_splitw(const float* __restrict__ W, half_t* __restrict__ out, int ncols) {
    int col = blockIdx.x;
    int k = threadIdx.x;
    float v = W[(size_t)k * ncols + col];
    half_t h = (half_t)v;
    out[(size_t)col * 256 + k] = h;
    out[(size_t)ncols * 256 + (size_t)col * 256 + k] = (half_t)(v - (float)h);
}

// ---------------- mixed fp16/fp32-A MFMA GEMM ----------------
// C = relu?(bias + A1@B1 [+ A2@B2]); K=256. B pre-split hi|lo fp16 [col][k].
// A1: fp32 (split on the fly, 3 MFMA/term) if !A1H, else fp16 (2 MFMA/term).
// A2: always fp16 (2 MFMA/term). OUTH: write C as fp16 (else fp32).
// Full-width BN tile => in-place C==A2 race-free.
template <int BN, bool A1H, bool HASA2, bool OUTH>
__global__ __launch_bounds__(512, 4) void k_gemm_mfma(
    const void* __restrict__ A1v, const half_t* __restrict__ B1,
    const half_t* __restrict__ A2h, const half_t* __restrict__ B2,
    const float* __restrict__ bias, void* __restrict__ Cv,
    int M, int doRelu) {
    constexpr int WNW = BN / 4;
    constexpr int NF = WNW / 16;
    __shared__ f16x8 sAhi[512];
    __shared__ f16x8 sAlo[512];
    __shared__ f16x8 sB[8 * BN];

    const int tid = threadIdx.x;
    const int lane = tid & 63;
    const int m0 = blockIdx.x * 128;
    const int skg = tid >> 7;
    const int srow = tid & 127;
    const int grow = min(m0 + srow, M - 1);
    const int l16 = lane & 15, fkg = lane >> 4;
    const int wid = tid >> 6, wm = wid >> 2, wn = wid & 3;
    const int aBase = fkg * 128 + wm * 64 + l16;
    const int bBase = fkg * BN + wn * WNW + l16;

    f32x4 acc[4][NF] = {};
    constexpr int NOPS = HASA2 ? 2 : 1;

#pragma unroll
    for (int op = 0; op < NOPS; ++op) {
        const bool aHalf = op ? true : A1H;
        const half_t* B = op ? B2 : B1;
        const half_t* Ah = op ? A2h : (const half_t*)A1v;
        const float* aptr = (const float*)A1v + (size_t)grow * 256 + skg * 8;
        float4 f0, f1;
        if (!aHalf) {
            f0 = *reinterpret_cast<const float4*>(aptr);
            f1 = *reinterpret_cast<const float4*>(aptr + 4);
        }

        for (int s = 0; s < 8; ++s) {
            const int kk = s * 32;
            __syncthreads();  // previous compute done; LDS free
            // B tiles (hi+lo) -> LDS, async direct
#pragma unroll
            for (int b = 0; b < BN / 128; ++b) {
                int c = tid + b * 512;
                int col = c & (BN - 1);
                int ckg = (BN == 256) ? (c >> 8) : (c >> 7);
                const half_t* bh = B + (size_t)col * 256 + kk + ckg * 8;
                GLOAD_LDS16(bh, &sB[c]);
                GLOAD_LDS16(bh + (size_t)BN * 256, &sB[4 * BN + c]);
            }
            // A chunk -> LDS
            if (aHalf) {
                GLOAD_LDS16(Ah + (size_t)grow * 256 + kk + skg * 8, &sAhi[tid]);
            } else {
                float fv[8] = {f0.x, f0.y, f0.z, f0.w, f1.x, f1.y, f1.z, f1.w};
                f16x8 hi, lo;
#pragma unroll
                for (int j = 0; j < 8; ++j) {
                    half_t h = (half_t)fv[j];
                    hi[j] = h;
                    lo[j] = (half_t)(fv[j] - (float)h);
                }
                sAhi[tid] = hi;
                sAlo[tid] = lo;
            }
            __syncthreads();  // drains vmcnt + lgkm
            if (!aHalf && s < 7) {
                f0 = *reinterpret_cast<const float4*>(aptr + (s + 1) * 32);
                f1 = *reinterpret_cast<const float4*>(aptr + (s + 1) * 32 + 4);
            }
            f16x8 ah[4], al[4];
#pragma unroll
            for (int mf = 0; mf < 4; ++mf) {
                ah[mf] = sAhi[aBase + mf * 16];
                if (!aHalf) al[mf] = sAlo[aBase + mf * 16];
            }
#pragma unroll
            for (int nf = 0; nf < NF; ++nf) {
                f16x8 bh = sB[bBase + nf * 16];
                f16x8 bl = sB[4 * BN + bBase + nf * 16];
#pragma unroll
                for (int mf = 0; mf < 4; ++mf) {
                    acc[mf][nf] = __builtin_amdgcn_mfma_f32_16x16x32_f16(ah[mf], bh, acc[mf][nf], 0, 0, 0);
                    if (!aHalf)
                        acc[mf][nf] = __builtin_amdgcn_mfma_f32_16x16x32_f16(al[mf], bh, acc[mf][nf], 0, 0, 0);
                    acc[mf][nf] = __builtin_amdgcn_mfma_f32_16x16x32_f16(ah[mf], bl, acc[mf][nf], 0, 0, 0);
                }
            }
        }
    }

    // epilogue: row = wm*64+mf*16+(lane>>4)*4+r, col = wn*WNW+nf*16+l16
#pragma unroll
    for (int mf = 0; mf < 4; ++mf) {
        int row = m0 + wm * 64 + mf * 16 + (lane >> 4) * 4;
#pragma unroll
        for (int nf = 0; nf < NF; ++nf) {
            int col = wn * WNW + nf * 16 + l16;
            float bv = bias[col];
#pragma unroll
            for (int r = 0; r < 4; ++r) {
                int gr = row + r;
                if (gr < M) {
                    float v = acc[mf][nf][r] + bv;
                    if (doRelu) v = fmaxf(v, 0.f);
                    if (OUTH)
                        ((half_t*)Cv)[(size_t)gr * BN + col] = (half_t)v;
                    else
                        ((float*)Cv)[(size_t)gr * BN + col] = v;
                }
            }
        }
    }
}

// ---------------- head: out = h @ W2 + b2   (128 -> 4) ----------------
__global__ void k_head(const float* __restrict__ h, const float* __restrict__ W2,
                       const float* __restrict__ b2, float* __restrict__ out) {
    int wave = threadIdx.x >> 6, lane = threadIdx.x & 63;
    int node = blockIdx.x * 4 + wave;
    const float* hr = h + (size_t)node * 128;
    float p0 = 0.f, p1 = 0.f, p2 = 0.f, p3 = 0.f;
    for (int j = lane; j < 128; j += 64) {
        float hv = hr[j];
        p0 += hv * W2[j * 4 + 0];
        p1 += hv * W2[j * 4 + 1];
        p2 += hv * W2[j * 4 + 2];
        p3 += hv * W2[j * 4 + 3];
    }
    for (int off = 32; off; off >>= 1) {
        p0 += __shfl_down(p0, off);
        p1 += __shfl_down(p1, off);
        p2 += __shfl_down(p2, off);
        p3 += __shfl_down(p3, off);
    }
    if (lane == 0) {
        float4 o = {p0 + b2[0], p1 + b2[1], p2 + b2[2], p3 + b2[3]};
        *reinterpret_cast<float4*>(out + (size_t)node * 4) = o;
    }
}

extern "C" void kernel_launch(void* const* d_in, const int* in_sizes, int n_in,
                              void* d_out, int out_size, void* d_ws, size_t ws_size,
                              hipStream_t stream) {
    const float* x  = (const float*)d_in[0];
    const int*   ei = (const int*)d_in[1];
    const float* Wl = (const float*)d_in[2];
    const float* bl = (const float*)d_in[3];
    const float* Wr = (const float*)d_in[4];
    const float* W1 = (const float*)d_in[5];
    const float* b1 = (const float*)d_in[6];
    const float* W2 = (const float*)d_in[7];
    const float* b2 = (const float*)d_in[8];
    float* out = (float*)d_out;

    char* w = (char*)d_ws;
    size_t o = 0;
    auto alloc = [&](size_t bytes) -> void* {
        void* p = w + o;
        o += (bytes + 255) & ~(size_t)255;
        return p;
    };
    int* deg     = (int*)alloc((size_t)N_NODES * 4);
    int* cursor  = (int*)alloc((size_t)N_NODES * 4);
    int* offsets = (int*)alloc((size_t)N_NODES * 4);
    int* bsum    = (int*)alloc((size_t)NBLK * 4);
    int* bscan   = (int*)alloc((size_t)NBLK * 4);
    int* csr     = (int*)alloc((size_t)N_EDGES * 4);
    float* agg   = (float*)alloc((size_t)N_NODES * HID * 4);   // fp32 agg / MLP hidden
    half_t* xh   = (half_t*)alloc((size_t)N_NODES * HID * 2);  // fp16 features (in-place)
    half_t* WlT[3]; half_t* WrT[3];
    for (int l = 0; l < 3; ++l) {
        WlT[l] = (half_t*)alloc((size_t)256 * 256 * 2 * 2);
        WrT[l] = (half_t*)alloc((size_t)256 * 256 * 2 * 2);
    }
    half_t* W1T = (half_t*)alloc((size_t)128 * 256 * 2 * 2);
    float* h = agg;  // MLP GEMM reads xh only -> safe to write h into agg

    const int* srcA = ei;
    const int* dstA = ei + N_EDGES;

    for (int l = 0; l < 3; ++l) {
        k_splitw<<<256, 256, 0, stream>>>(Wl + (size_t)l * 65536, WlT[l], 256);
        k_splitw<<<256, 256, 0, stream>>>(Wr + (size_t)l * 65536, WrT[l], 256);
    }
    k_splitw<<<128, 256, 0, stream>>>(W1, W1T, 128);
    k_tohalf<<<(N_NODES * HID / 8 + 255) / 256, 256, 0, stream>>>(x, xh, N_NODES * HID / 8);

    hipMemsetAsync(deg, 0, (size_t)N_NODES * 4, stream);
    k_count<<<(N_EDGES + 255) / 256, 256, 0, stream>>>(dstA, deg);
    k_blocksum<<<NBLK, 256, 0, stream>>>(deg, bsum);
    k_scan_bsum<<<1, 64, 0, stream>>>(bsum, bscan);
    k_scan_final<<<NBLK, 256, 0, stream>>>(deg, bscan, offsets, cursor);
    k_fill<<<(N_EDGES + 255) / 256, 256, 0, stream>>>(srcA, dstA, cursor, csr);

    const int mblocks = (N_NODES + 127) / 128;
    for (int l = 0; l < 3; ++l) {
        k_aggregate_h<<<N_NODES / 4, 256, 0, stream>>>(xh, offsets, deg, csr, agg);
        // feat(fp16, in-place in xh) = relu(bl + agg@Wl + feat@Wr)
        k_gemm_mfma<256, false, true, true><<<mblocks, 512, 0, stream>>>(
            agg, WlT[l], xh, WrT[l], bl + (size_t)l * 256, xh, N_NODES, 1);
    }
    // h(fp32) = relu(feat@W1 + b1)
    k_gemm_mfma<128, true, false, false><<<mblocks, 512, 0, stream>>>(
        xh, W1T, nullptr, nullptr, b1, h, N_NODES, 1);
    k_head<<<N_NODES / 4, 256, 0, stream>>>(h, W2, b2, out);
}